// Round 25
// baseline (204.186 us; speedup 1.0000x reference)
//
#include <hip/hip_runtime.h>
#include <stdint.h>

// ---------- types ----------
typedef __bf16 bf16x8 __attribute__((ext_vector_type(8)));
typedef _Float16 f16x8 __attribute__((ext_vector_type(8)));
typedef float f32x4 __attribute__((ext_vector_type(4)));
typedef short s16x8 __attribute__((ext_vector_type(8)));
typedef short s16x4 __attribute__((ext_vector_type(4)));
typedef unsigned int u32x4 __attribute__((ext_vector_type(4)));

__device__ __forceinline__ unsigned short f2bf(float f) {
  unsigned u = __builtin_bit_cast(unsigned, f);
  u += 0x7fff + ((u >> 16) & 1);   // RNE
  return (unsigned short)(u >> 16);
}
__device__ __forceinline__ unsigned short f2h(float f) {
  return __builtin_bit_cast(unsigned short, (_Float16)f);
}
__device__ __forceinline__ float exp2i(float x) {    // v_exp_f32 = 2^x
  float r;
  asm("v_exp_f32 %0, %1" : "=v"(r) : "v"(x));
  return r;
}
__device__ __forceinline__ float max3f(float a, float b, float c) {
  float r;
  asm("v_max3_f32 %0, %1, %2, %3" : "=v"(r) : "v"(a), "v"(b), "v"(c));
  return r;
}
__device__ __forceinline__ unsigned cvtpkh(float lo, float hi) {  // 2xf32 -> packed fp16
  auto r = __builtin_amdgcn_cvt_pkrtz(lo, hi);
  return __builtin_bit_cast(unsigned, r);
}

__device__ __forceinline__ void gload_lds16(const void* g, void* l) {
  __builtin_amdgcn_global_load_lds(
      (const __attribute__((address_space(1))) unsigned int*)g,
      (__attribute__((address_space(3))) unsigned int*)l, 16, 0, 0);
}

__device__ __forceinline__ f32x4 mfma_bf(bf16x8 a, bf16x8 b, f32x4 c) {
  return __builtin_amdgcn_mfma_f32_16x16x32_bf16(a, b, c, 0, 0, 0);
}
__device__ __forceinline__ f32x4 mfma_h(f16x8 a, f16x8 b, f32x4 c) {
  return __builtin_amdgcn_mfma_f32_16x16x32_f16(a, b, c, 0, 0, 0);
}
__device__ __forceinline__ bf16x8 bc8(s16x8 v) { return __builtin_bit_cast(bf16x8, v); }
__device__ __forceinline__ f16x8 hc8(s16x8 v) { return __builtin_bit_cast(f16x8, v); }

// ---------- fp32 -> bf16 convert (x, w_qkv, w_proj in one launch) ----------
__global__ void k_cvt_all(const float* __restrict__ x, const float* __restrict__ wq,
                          const float* __restrict__ wp,
                          unsigned short* __restrict__ xb,
                          unsigned short* __restrict__ wqb,
                          unsigned short* __restrict__ wpb) {
  int i = blockIdx.x * blockDim.x + threadIdx.x;
  const float* in; unsigned short* out; int j = i;
  if (i < 2097152)        { in = x;  out = xb;  }
  else if (i < 2883584)   { in = wq; out = wqb; j = i - 2097152; }
  else                    { in = wp; out = wpb; j = i - 2883584; }
  float4 v = ((const float4*)in)[j];
  ushort4 o;
  o.x = f2bf(v.x); o.y = f2bf(v.y); o.z = f2bf(v.z); o.w = f2bf(v.w);
  ((ushort4*)out)[j] = o;
}

// ---------- QKV GEMM: 256x256 tile, 1024 thr (16 waves 4x4), BK=64 ----------
// Same per-wave 64x64 fragment code (bit-identical outputs); A and B re-reads
// both halved vs 256x128 (384 blocks x 1MB operands); barrier-sec/output halved.
__global__ __launch_bounds__(1024) void k_gemm_qkv(
    const unsigned short* __restrict__ A, const unsigned short* __restrict__ Bm,
    unsigned short* __restrict__ Qf, unsigned short* __restrict__ Kf,
    unsigned short* __restrict__ Vb,
    const float* __restrict__ sin_t, const float* __restrict__ cos_t) {
  const int M_K = 1024;
  __shared__ unsigned short As[256 * 64];
  __shared__ unsigned short Bs[256 * 64];
  const int tid = threadIdx.x;
  const int lane = tid & 63;
  const int l15 = lane & 15, g = lane >> 4;
  const int wid = tid >> 6, wr = wid >> 2, wc = wid & 3;   // 4x4 waves
  const int lid = blockIdx.y * 12 + blockIdx.x;      // 384 blocks (12 n, 32 m)
  const int swz = (lid & 7) * 48 + (lid >> 3);       // XCD-chunked, bijective
  const int by = swz / 12, bx = swz - by * 12;
  const long m0 = (long)by * 256, n0 = (long)bx * 256;

  const int sc = (tid & 7) ^ ((tid >> 3) & 7);       // p-invariant swizzle
  f32x4 acc[4][4] = {};

  for (int k0 = 0; k0 < M_K; k0 += 64) {
#pragma unroll
    for (int p = 0; p < 2; ++p) {                    // 2048 units each
      int u = p * 1024 + tid;
      int row = (tid >> 3) + p * 128;
      gload_lds16(A + (m0 + row) * M_K + k0 + sc * 8, (char*)As + u * 16);
      gload_lds16(Bm + (n0 + row) * M_K + k0 + sc * 8, (char*)Bs + u * 16);
    }
    __syncthreads();
    bf16x8 af[4][2], bfr[4][2];
#pragma unroll
    for (int i = 0; i < 4; ++i) {
#pragma unroll
      for (int kk = 0; kk < 2; ++kk) {
        int ua = ((kk * 4 + g) ^ (l15 & 7));
        af[i][kk]  = bc8(*(const s16x8*)&As[(wr * 64 + i * 16 + l15) * 64 + ua * 8]);
        bfr[i][kk] = bc8(*(const s16x8*)&Bs[(wc * 64 + i * 16 + l15) * 64 + ua * 8]);
      }
    }
#pragma unroll
    for (int mi = 0; mi < 4; ++mi)
#pragma unroll
      for (int ni = 0; ni < 4; ++ni) {
        acc[mi][ni] = mfma_bf(af[mi][0], bfr[ni][0], acc[mi][ni]);
        acc[mi][ni] = mfma_bf(af[mi][1], bfr[ni][1], acc[mi][ni]);
      }
    __syncthreads();
  }

  const int colbase = (int)n0 + wc * 64;
  const int s  = colbase >> 10;           // 0=q 1=k 2=v
  const int h  = (colbase >> 6) & 15;
  const float QSC = 0.125f * 1.44269504089f;
#pragma unroll
  for (int mi = 0; mi < 4; ++mi)
#pragma unroll
    for (int r = 0; r < 4; ++r) {
      long m = m0 + wr * 64 + mi * 16 + g * 4 + r;
      int b = (int)(m >> 11), n = (int)(m & 2047);
      long slab = ((long)(b * 16 + h)) * 131072 + (long)n * 64;
      float v0 = acc[mi][0][r], v1 = acc[mi][1][r];
      float v2 = acc[mi][2][r], v3 = acc[mi][3][r];
      if (s == 2) {
        Vb[slab + l15]      = f2h(v0);
        Vb[slab + 16 + l15] = f2h(v1);
        Vb[slab + 32 + l15] = f2h(v2);
        Vb[slab + 48 + l15] = f2h(v3);
      } else {
        float o0 = v0, o1 = v1, o2 = v2, o3 = v3;
        if (n >= 4) {
          const float* cs = cos_t + (long)(n - 4) * 64;
          const float* sn = sin_t + (long)(n - 4) * 64;
          float c0 = cs[l15], c1 = cs[16 + l15], c2 = cs[32 + l15], c3 = cs[48 + l15];
          float s0 = sn[l15], s1 = sn[16 + l15], s2 = sn[32 + l15], s3 = sn[48 + l15];
          float t0 = o0, t1 = o1;
          o0 = o0 * c0 - o2 * s0;  o1 = o1 * c1 - o3 * s1;
          o2 = o2 * c2 + t0 * s2;  o3 = o3 * c3 + t1 * s3;
        }
        if (s == 0) { o0 *= QSC; o1 *= QSC; o2 *= QSC; o3 *= QSC; }
        unsigned short* H = (s == 0) ? Qf : Kf;
        H[slab + l15]      = f2h(o0);
        H[slab + 16 + l15] = f2h(o1);
        H[slab + 32 + l15] = f2h(o2);
        H[slab + 48 + l15] = f2h(o3);
      }
    }
}

// ---------- V transpose + key-permute ----------
__global__ __launch_bounds__(256) void k_vtrans(const unsigned short* __restrict__ Vb,
                                                unsigned short* __restrict__ Vt) {
  __shared__ unsigned short T[64 * 256];
  const int tid = threadIdx.x;
  const int bh = blockIdx.y;
  const int n0 = blockIdx.x * 256;
  const long slab = (long)bh * 131072;
#pragma unroll
  for (int it = 0; it < 8; ++it) {
    int u = it * 256 + tid;
    int key = u >> 3, dc = u & 7;
    s16x8 v = *(const s16x8*)&Vb[slab + (long)(n0 + key) * 64 + dc * 8];
#pragma unroll
    for (int i = 0; i < 8; ++i) {
      int d = dc * 8 + i;
      T[d * 256 + (key ^ (dc << 3))] = (unsigned short)v[i];
    }
  }
  __syncthreads();
#pragma unroll
  for (int it = 0; it < 8; ++it) {
    int w = it * 256 + tid;
    int d = w >> 5, uc = w & 31;           // uc: 16B-unit within 256-key row
    int tile = uc >> 3, unit = uc & 7;
    int hh = unit >> 2, gg = unit & 3;
    int ka = tile * 64 + hh * 16 + gg * 4; // keys ka..ka+3 and ka+32..ka+35
    int dc = d >> 3;
    s16x4 a = *(const s16x4*)&T[d * 256 + (ka ^ (dc << 3))];
    s16x4 b = *(const s16x4*)&T[d * 256 + ((ka + 32) ^ (dc << 3))];
    s16x8 v = {a[0], a[1], a[2], a[3], b[0], b[1], b[2], b[3]};
    *(s16x8*)&Vt[slab + (long)d * 2048 + n0 + uc * 8] = v;
  }
}

// ---------- projection GEMM (BK=64, XOR-swizzled LDS), f32 out + bias ----------
__global__ __launch_bounds__(256) void k_gemm_proj(
    const unsigned short* __restrict__ A, const unsigned short* __restrict__ Bm,
    float* __restrict__ Cf, const float* __restrict__ bias, int M, int N, int K) {
  __shared__ unsigned short As[128 * 64];
  __shared__ unsigned short Bs[128 * 64];
  const int tid = threadIdx.x;
  const int lane = tid & 63;
  const int l15 = lane & 15, g = lane >> 4;
  const int wid = tid >> 6, wr = wid >> 1, wc = wid & 1;
  const int lid = blockIdx.y * 8 + blockIdx.x;       // 512 blocks
  const int swz = (lid & 7) * 64 + (lid >> 3);       // XCD-chunked, bijective
  const int by = swz >> 3, bx = swz & 7;
  const long m0 = (long)by * 128, n0 = (long)bx * 128;

  const int srow = tid >> 3, scu = tid & 7, sc = scu ^ (srow & 7);
  f32x4 acc[4][4] = {};

  for (int k0 = 0; k0 < K; k0 += 64) {
#pragma unroll
    for (int p = 0; p < 4; ++p) {
      int u = p * 256 + tid;
      int row = srow + p * 32;
      gload_lds16(A + (m0 + row) * K + k0 + sc * 8, (char*)As + u * 16);
      gload_lds16(Bm + (n0 + row) * K + k0 + sc * 8, (char*)Bs + u * 16);
    }
    __syncthreads();
    bf16x8 af[4][2], bfr[4][2];
#pragma unroll
    for (int i = 0; i < 4; ++i) {
#pragma unroll
      for (int kk = 0; kk < 2; ++kk) {
        int ua = ((kk * 4 + g) ^ (l15 & 7));
        af[i][kk]  = bc8(*(const s16x8*)&As[(wr * 64 + i * 16 + l15) * 64 + ua * 8]);
        bfr[i][kk] = bc8(*(const s16x8*)&Bs[(wc * 64 + i * 16 + l15) * 64 + ua * 8]);
      }
    }
#pragma unroll
    for (int mi = 0; mi < 4; ++mi)
#pragma unroll
      for (int ni = 0; ni < 4; ++ni) {
        acc[mi][ni] = mfma_bf(af[mi][0], bfr[ni][0], acc[mi][ni]);
        acc[mi][ni] = mfma_bf(af[mi][1], bfr[ni][1], acc[mi][ni]);
      }
    __syncthreads();
  }

#pragma unroll
  for (int mi = 0; mi < 4; ++mi)
#pragma unroll
    for (int ni = 0; ni < 4; ++ni) {
      long col = n0 + wc * 64 + ni * 16 + l15;
#pragma unroll
      for (int r = 0; r < 4; ++r) {
        long row = m0 + wr * 64 + mi * 16 + g * 4 + r;
        Cf[row * N + col] = acc[mi][ni][r] + bias[col];
      }
    }
}

// ---------- MFMA flash attention (fp16, KVBLK=256, 8 rounds, 512 thr) ----------
// r23/r24 kernel verbatim (banked, 95.7 us).
__global__ __launch_bounds__(512) void k_flash(
    const unsigned short* __restrict__ Qf, const unsigned short* __restrict__ Kf,
    const unsigned short* __restrict__ Vt, unsigned short* __restrict__ o) {
  __shared__ unsigned short KS[2][256 * 64];
  __shared__ unsigned short VtS[2][64 * 256];
  const int tid = threadIdx.x;
  const int lane = tid & 63, wid = tid >> 6;       // wid 0..7
  const int l15 = lane & 15, g = lane >> 4;
  const int j = blockIdx.x;                        // 512 blocks
  const int c = j & 7, s = j >> 3;                 // s 0..63
  const int bh = ((s >> 3) << 3) | c;              // bijective: bh in [0,64)
  const int qt = s & 7;
  const int b = bh >> 4, h = bh & 15;
  const int q0 = qt * 256 + wid * 32;
  const long slab = (long)bh * 131072;

  const long qrowA = slab + (long)(q0 + l15) * 64;
  const long qrowB = slab + (long)(q0 + 16 + l15) * 64;
  f16x8 qa0 = hc8(*(const s16x8*)&Qf[qrowA + g * 8]);
  f16x8 qa1 = hc8(*(const s16x8*)&Qf[qrowA + 32 + g * 8]);
  f16x8 qb0 = hc8(*(const s16x8*)&Qf[qrowB + g * 8]);
  f16x8 qb1 = hc8(*(const s16x8*)&Qf[qrowB + 32 + g * 8]);

  const u32x4 ones_raw = {0x3c003c00u, 0x3c003c00u, 0x3c003c00u, 0x3c003c00u};
  const f16x8 ones = __builtin_bit_cast(f16x8, ones_raw);

  f32x4 ova[4] = {}, ovb[4] = {};
  f32x4 lacA = {}, lacB = {};              // softmax denominators (via ones-MFMA)
  float mrunA = -1e30f, mrunB = -1e30f;

  const int cK = (tid & 7) ^ ((tid >> 3) & 7);
  const int cV = (tid & 31) ^ ((tid >> 5) & 7);
  const unsigned short* kSrc = Kf + slab + (long)(tid >> 3) * 64 + cK * 8;
  const unsigned short* vSrc = Vt + slab + (long)(tid >> 5) * 2048 + cV * 8;

  auto stage = [&](int buf) {
#pragma unroll
    for (int p = 0; p < 4; ++p) {
      gload_lds16(kSrc + p * 4096,  (char*)&KS[buf][0]  + (p * 512 + tid) * 16);
      gload_lds16(vSrc + p * 32768, (char*)&VtS[buf][0] + (p * 512 + tid) * 16);
    }
    kSrc += 16384;  // next 256-key group: 256 rows x 64
    vSrc += 256;    // next 256 keys along the 2048-key rows
  };

  stage(0);
  __syncthreads();                  // round 0 fully resident (all waves)

  for (int t = 0; t < 8; ++t) {
    const int cur = t & 1;
    if (t < 7) stage(cur ^ 1);      // prefetch; drains at end-of-round barrier

#pragma unroll
    for (int hf = 0; hf < 2; ++hf) {   // two 128-key halves per barrier round
      // QK^T over 128 keys
      f32x4 sa[8], sb[8];
      __builtin_amdgcn_s_setprio(1);
#pragma unroll
      for (int kt = 0; kt < 8; ++kt) {
        f32x4 xa = {}, xb = {};
#pragma unroll
        for (int kk = 0; kk < 2; ++kk) {
          int row = hf * 128 + kt * 16 + l15;
          int uu = row * 8 + ((kk * 4 + g) ^ (row & 7));
          f16x8 kf = hc8(*(const s16x8*)&KS[cur][uu * 8]);
          xa = mfma_h(kf, kk ? qa1 : qa0, xa);
          xb = mfma_h(kf, kk ? qb1 : qb0, xb);
        }
        sa[kt] = xa; sb[kt] = xb;
      }
      __builtin_amdgcn_s_setprio(0);

      // per-query half max via v_max3 chains
      float ta = fmaxf(sa[0][0], sa[0][1]);
      ta = max3f(ta, sa[0][2], sa[0][3]);
      float tb = fmaxf(sb[0][0], sb[0][1]);
      tb = max3f(tb, sb[0][2], sb[0][3]);
#pragma unroll
      for (int kt = 1; kt < 8; ++kt) {
        ta = max3f(ta, sa[kt][0], sa[kt][1]);
        ta = max3f(ta, sa[kt][2], sa[kt][3]);
        tb = max3f(tb, sb[kt][0], sb[kt][1]);
        tb = max3f(tb, sb[kt][2], sb[kt][3]);
      }
      ta = fmaxf(ta, __shfl_xor(ta, 16)); ta = fmaxf(ta, __shfl_xor(ta, 32));
      tb = fmaxf(tb, __shfl_xor(tb, 16)); tb = fmaxf(tb, __shfl_xor(tb, 32));

      // defer-max (THR=8 in log2 units; P bounded by 2^8, fp16-safe)
      if (!__all(ta <= mrunA + 8.f && tb <= mrunB + 8.f)) {
        float mA = fmaxf(mrunA, ta), mB = fmaxf(mrunB, tb);
        float cA = exp2i(mrunA - mA), cB = exp2i(mrunB - mB);
        lacA *= cA; lacB *= cB;
#pragma unroll
        for (int dt = 0; dt < 4; ++dt) { ova[dt] *= cA; ovb[dt] *= cB; }
        mrunA = mA; mrunB = mB;
      }

      unsigned pa[8][2], pbv[8][2];
#pragma unroll
      for (int kt = 0; kt < 8; ++kt) {
        float a0 = exp2i(sa[kt][0] - mrunA), a1 = exp2i(sa[kt][1] - mrunA);
        float a2 = exp2i(sa[kt][2] - mrunA), a3 = exp2i(sa[kt][3] - mrunA);
        float b0 = exp2i(sb[kt][0] - mrunB), b1 = exp2i(sb[kt][1] - mrunB);
        float b2 = exp2i(sb[kt][2] - mrunB), b3 = exp2i(sb[kt][3] - mrunB);
        pa[kt][0]  = cvtpkh(a0, a1); pa[kt][1]  = cvtpkh(a2, a3);
        pbv[kt][0] = cvtpkh(b0, b1); pbv[kt][1] = cvtpkh(b2, b3);
      }

      // PV over this half's two 64-key subtiles (st = hf*2 + ktile)
      __builtin_amdgcn_s_setprio(1);
#pragma unroll
      for (int ktile = 0; ktile < 2; ++ktile) {
        int kb = ktile * 4;
#pragma unroll
        for (int h2 = 0; h2 < 2; ++h2) {
          u32x4 brawA = {pa[kb + h2][0], pa[kb + h2][1],
                         pa[kb + h2 + 2][0], pa[kb + h2 + 2][1]};
          u32x4 brawB = {pbv[kb + h2][0], pbv[kb + h2][1],
                         pbv[kb + h2 + 2][0], pbv[kb + h2 + 2][1]};
          f16x8 pfA = __builtin_bit_cast(f16x8, brawA);
          f16x8 pfB = __builtin_bit_cast(f16x8, brawB);
          lacA = mfma_h(ones, pfA, lacA);
          lacB = mfma_h(ones, pfB, lacB);
#pragma unroll
          for (int dt = 0; dt < 4; ++dt) {
            int d = dt * 16 + l15;
            int vv = d * 32 + (hf * 2 + ktile) * 8 + ((h2 * 4 + g) ^ (d & 7));
            f16x8 vf = hc8(*(const s16x8*)&VtS[cur][vv * 8]);
            ova[dt] = mfma_h(vf, pfA, ova[dt]);
            ovb[dt] = mfma_h(vf, pfB, ovb[dt]);
          }
        }
      }
      __builtin_amdgcn_s_setprio(0);
    }
    __syncthreads();   // drains this wave's prefetch + barriers all waves
  }

  // lacA/lacB: every lane already holds the full-key denominator for its query
  float rA = 1.0f / lacA[0], rB = 1.0f / lacB[0];
  long orowA = ((long)(b * 2048 + q0 + l15)) * 1024 + h * 64;
  long orowB = ((long)(b * 2048 + q0 + 16 + l15)) * 1024 + h * 64;
#pragma unroll
  for (int dt = 0; dt < 4; ++dt) {
    ushort4 wa, wb;
    wa.x = f2bf(ova[dt][0] * rA); wa.y = f2bf(ova[dt][1] * rA);
    wa.z = f2bf(ova[dt][2] * rA); wa.w = f2bf(ova[dt][3] * rA);
    wb.x = f2bf(ovb[dt][0] * rB); wb.y = f2bf(ovb[dt][1] * rB);
    wb.z = f2bf(ovb[dt][2] * rB); wb.w = f2bf(ovb[dt][3] * rB);
    *(ushort4*)&o[orowA + dt * 16 + g * 4] = wa;
    *(ushort4*)&o[orowB + dt * 16 + g * 4] = wb;
  }
}

// ---------- launcher ----------
extern "C" void kernel_launch(void* const* d_in, const int* in_sizes, int n_in,
                              void* d_out, int out_size, void* d_ws, size_t ws_size,
                              hipStream_t stream) {
  const float* x      = (const float*)d_in[0];
  const float* sin_t  = (const float*)d_in[1];
  const float* cos_t  = (const float*)d_in[2];
  const float* w_qkv  = (const float*)d_in[3];
  const float* w_proj = (const float*)d_in[4];
  const float* b_proj = (const float*)d_in[5];
  float* out = (float*)d_out;

  char* ws = (char*)d_ws;
  unsigned short* xb     = (unsigned short*)(ws);                 // 16 MiB
  unsigned short* wqkvb  = (unsigned short*)(ws + (16l << 20));   // 6 MiB
  unsigned short* wprojb = (unsigned short*)(ws + (22l << 20));   // 2 MiB
  unsigned short* Qf     = (unsigned short*)(ws + (24l << 20));   // 16 MiB
  unsigned short* Kf     = (unsigned short*)(ws + (40l << 20));   // 16 MiB
  unsigned short* Vb     = (unsigned short*)(ws + (56l << 20));   // 16 MiB
  unsigned short* Vt     = (unsigned short*)(ws + (72l << 20));   // 16 MiB
  unsigned short* ob     = xb;   // alias: xb dead after QKV GEMM

  k_cvt_all<<<12288, 256, 0, stream>>>(x, w_qkv, w_proj, xb, wqkvb, wprojb);

  k_gemm_qkv<<<dim3(12, 32), 1024, 0, stream>>>(xb, wqkvb, Qf, Kf, Vb,
                                                sin_t, cos_t);
  k_vtrans<<<dim3(8, 64), 256, 0, stream>>>(Vb, Vt);
  k_flash<<<dim3(512), 512, 0, stream>>>(Qf, Kf, Vt, ob);
  k_gemm_proj<<<dim3(8, 64), 256, 0, stream>>>(ob, wprojb, out, b_proj,
                                               8192, 1024, 1024);
}

// Round 26
// 193.428 us; speedup vs baseline: 1.0556x; 1.0556x over previous
//
#include <hip/hip_runtime.h>
#include <stdint.h>

// ---------- types ----------
typedef __bf16 bf16x8 __attribute__((ext_vector_type(8)));
typedef _Float16 f16x8 __attribute__((ext_vector_type(8)));
typedef float f32x4 __attribute__((ext_vector_type(4)));
typedef short s16x8 __attribute__((ext_vector_type(8)));
typedef short s16x4 __attribute__((ext_vector_type(4)));
typedef unsigned int u32x4 __attribute__((ext_vector_type(4)));

__device__ __forceinline__ unsigned short f2bf(float f) {
  unsigned u = __builtin_bit_cast(unsigned, f);
  u += 0x7fff + ((u >> 16) & 1);   // RNE
  return (unsigned short)(u >> 16);
}
__device__ __forceinline__ unsigned short f2h(float f) {
  return __builtin_bit_cast(unsigned short, (_Float16)f);
}
__device__ __forceinline__ float exp2i(float x) {    // v_exp_f32 = 2^x
  float r;
  asm("v_exp_f32 %0, %1" : "=v"(r) : "v"(x));
  return r;
}
__device__ __forceinline__ float max3f(float a, float b, float c) {
  float r;
  asm("v_max3_f32 %0, %1, %2, %3" : "=v"(r) : "v"(a), "v"(b), "v"(c));
  return r;
}
__device__ __forceinline__ unsigned cvtpkh(float lo, float hi) {  // 2xf32 -> packed fp16
  auto r = __builtin_amdgcn_cvt_pkrtz(lo, hi);
  return __builtin_bit_cast(unsigned, r);
}

__device__ __forceinline__ void gload_lds16(const void* g, void* l) {
  __builtin_amdgcn_global_load_lds(
      (const __attribute__((address_space(1))) unsigned int*)g,
      (__attribute__((address_space(3))) unsigned int*)l, 16, 0, 0);
}

__device__ __forceinline__ f32x4 mfma_bf(bf16x8 a, bf16x8 b, f32x4 c) {
  return __builtin_amdgcn_mfma_f32_16x16x32_bf16(a, b, c, 0, 0, 0);
}
__device__ __forceinline__ f32x4 mfma_h(f16x8 a, f16x8 b, f32x4 c) {
  return __builtin_amdgcn_mfma_f32_16x16x32_f16(a, b, c, 0, 0, 0);
}
__device__ __forceinline__ bf16x8 bc8(s16x8 v) { return __builtin_bit_cast(bf16x8, v); }
__device__ __forceinline__ f16x8 hc8(s16x8 v) { return __builtin_bit_cast(f16x8, v); }

// ---------- fp32 -> bf16 convert (x, w_qkv, w_proj in one launch) ----------
__global__ void k_cvt_all(const float* __restrict__ x, const float* __restrict__ wq,
                          const float* __restrict__ wp,
                          unsigned short* __restrict__ xb,
                          unsigned short* __restrict__ wqb,
                          unsigned short* __restrict__ wpb) {
  int i = blockIdx.x * blockDim.x + threadIdx.x;
  const float* in; unsigned short* out; int j = i;
  if (i < 2097152)        { in = x;  out = xb;  }
  else if (i < 2883584)   { in = wq; out = wqb; j = i - 2097152; }
  else                    { in = wp; out = wpb; j = i - 2883584; }
  float4 v = ((const float4*)in)[j];
  ushort4 o;
  o.x = f2bf(v.x); o.y = f2bf(v.y); o.z = f2bf(v.z); o.w = f2bf(v.w);
  ((ushort4*)out)[j] = o;
}

// ---------- QKV GEMM: 256x128 tile, 512 thr (8 waves 4x2), BK=64 ----------
// r24 kernel verbatim (banked): halves B re-reads vs 128-tile; 768 blocks.
__global__ __launch_bounds__(512) void k_gemm_qkv(
    const unsigned short* __restrict__ A, const unsigned short* __restrict__ Bm,
    unsigned short* __restrict__ Qf, unsigned short* __restrict__ Kf,
    unsigned short* __restrict__ Vb,
    const float* __restrict__ sin_t, const float* __restrict__ cos_t) {
  const int M_K = 1024;
  __shared__ unsigned short As[256 * 64];
  __shared__ unsigned short Bs[128 * 64];
  const int tid = threadIdx.x;
  const int lane = tid & 63;
  const int l15 = lane & 15, g = lane >> 4;
  const int wid = tid >> 6, wr = wid >> 1, wc = wid & 1;   // 4x2 waves
  const int lid = blockIdx.y * 24 + blockIdx.x;      // 768 blocks (24 n, 32 m)
  const int swz = (lid & 7) * 96 + (lid >> 3);       // XCD-chunked, bijective
  const int by = swz / 24, bx = swz - by * 24;
  const long m0 = (long)by * 256, n0 = (long)bx * 128;

  const int sc = (tid & 7) ^ ((tid >> 3) & 7);       // p-invariant swizzle
  f32x4 acc[4][4] = {};

  for (int k0 = 0; k0 < M_K; k0 += 64) {
#pragma unroll
    for (int p = 0; p < 4; ++p) {                    // As: 2048 units
      int u = p * 512 + tid;
      int row = (tid >> 3) + p * 64;
      gload_lds16(A + (m0 + row) * M_K + k0 + sc * 8, (char*)As + u * 16);
    }
#pragma unroll
    for (int p = 0; p < 2; ++p) {                    // Bs: 1024 units
      int u = p * 512 + tid;
      int row = (tid >> 3) + p * 64;
      gload_lds16(Bm + (n0 + row) * M_K + k0 + sc * 8, (char*)Bs + u * 16);
    }
    __syncthreads();
    bf16x8 af[4][2], bfr[4][2];
#pragma unroll
    for (int i = 0; i < 4; ++i) {
#pragma unroll
      for (int kk = 0; kk < 2; ++kk) {
        int ua = ((kk * 4 + g) ^ (l15 & 7));
        af[i][kk]  = bc8(*(const s16x8*)&As[(wr * 64 + i * 16 + l15) * 64 + ua * 8]);
        bfr[i][kk] = bc8(*(const s16x8*)&Bs[(wc * 64 + i * 16 + l15) * 64 + ua * 8]);
      }
    }
#pragma unroll
    for (int mi = 0; mi < 4; ++mi)
#pragma unroll
      for (int ni = 0; ni < 4; ++ni) {
        acc[mi][ni] = mfma_bf(af[mi][0], bfr[ni][0], acc[mi][ni]);
        acc[mi][ni] = mfma_bf(af[mi][1], bfr[ni][1], acc[mi][ni]);
      }
    __syncthreads();
  }

  const int colbase = (int)n0 + wc * 64;
  const int s  = colbase >> 10;           // 0=q 1=k 2=v
  const int h  = (colbase >> 6) & 15;
  const float QSC = 0.125f * 1.44269504089f;
#pragma unroll
  for (int mi = 0; mi < 4; ++mi)
#pragma unroll
    for (int r = 0; r < 4; ++r) {
      long m = m0 + wr * 64 + mi * 16 + g * 4 + r;
      int b = (int)(m >> 11), n = (int)(m & 2047);
      long slab = ((long)(b * 16 + h)) * 131072 + (long)n * 64;
      float v0 = acc[mi][0][r], v1 = acc[mi][1][r];
      float v2 = acc[mi][2][r], v3 = acc[mi][3][r];
      if (s == 2) {
        Vb[slab + l15]      = f2h(v0);
        Vb[slab + 16 + l15] = f2h(v1);
        Vb[slab + 32 + l15] = f2h(v2);
        Vb[slab + 48 + l15] = f2h(v3);
      } else {
        float o0 = v0, o1 = v1, o2 = v2, o3 = v3;
        if (n >= 4) {
          const float* cs = cos_t + (long)(n - 4) * 64;
          const float* sn = sin_t + (long)(n - 4) * 64;
          float c0 = cs[l15], c1 = cs[16 + l15], c2 = cs[32 + l15], c3 = cs[48 + l15];
          float s0 = sn[l15], s1 = sn[16 + l15], s2 = sn[32 + l15], s3 = sn[48 + l15];
          float t0 = o0, t1 = o1;
          o0 = o0 * c0 - o2 * s0;  o1 = o1 * c1 - o3 * s1;
          o2 = o2 * c2 + t0 * s2;  o3 = o3 * c3 + t1 * s3;
        }
        if (s == 0) { o0 *= QSC; o1 *= QSC; o2 *= QSC; o3 *= QSC; }
        unsigned short* H = (s == 0) ? Qf : Kf;
        H[slab + l15]      = f2h(o0);
        H[slab + 16 + l15] = f2h(o1);
        H[slab + 32 + l15] = f2h(o2);
        H[slab + 48 + l15] = f2h(o3);
      }
    }
}

// ---------- V transpose + key-permute ----------
__global__ __launch_bounds__(256) void k_vtrans(const unsigned short* __restrict__ Vb,
                                                unsigned short* __restrict__ Vt) {
  __shared__ unsigned short T[64 * 256];
  const int tid = threadIdx.x;
  const int bh = blockIdx.y;
  const int n0 = blockIdx.x * 256;
  const long slab = (long)bh * 131072;
#pragma unroll
  for (int it = 0; it < 8; ++it) {
    int u = it * 256 + tid;
    int key = u >> 3, dc = u & 7;
    s16x8 v = *(const s16x8*)&Vb[slab + (long)(n0 + key) * 64 + dc * 8];
#pragma unroll
    for (int i = 0; i < 8; ++i) {
      int d = dc * 8 + i;
      T[d * 256 + (key ^ (dc << 3))] = (unsigned short)v[i];
    }
  }
  __syncthreads();
#pragma unroll
  for (int it = 0; it < 8; ++it) {
    int w = it * 256 + tid;
    int d = w >> 5, uc = w & 31;           // uc: 16B-unit within 256-key row
    int tile = uc >> 3, unit = uc & 7;
    int hh = unit >> 2, gg = unit & 3;
    int ka = tile * 64 + hh * 16 + gg * 4; // keys ka..ka+3 and ka+32..ka+35
    int dc = d >> 3;
    s16x4 a = *(const s16x4*)&T[d * 256 + (ka ^ (dc << 3))];
    s16x4 b = *(const s16x4*)&T[d * 256 + ((ka + 32) ^ (dc << 3))];
    s16x8 v = {a[0], a[1], a[2], a[3], b[0], b[1], b[2], b[3]};
    *(s16x8*)&Vt[slab + (long)d * 2048 + n0 + uc * 8] = v;
  }
}

// ---------- projection GEMM (BK=64, XOR-swizzled LDS), f32 out + bias ----------
__global__ __launch_bounds__(256) void k_gemm_proj(
    const unsigned short* __restrict__ A, const unsigned short* __restrict__ Bm,
    float* __restrict__ Cf, const float* __restrict__ bias, int M, int N, int K) {
  __shared__ unsigned short As[128 * 64];
  __shared__ unsigned short Bs[128 * 64];
  const int tid = threadIdx.x;
  const int lane = tid & 63;
  const int l15 = lane & 15, g = lane >> 4;
  const int wid = tid >> 6, wr = wid >> 1, wc = wid & 1;
  const int lid = blockIdx.y * 8 + blockIdx.x;       // 512 blocks
  const int swz = (lid & 7) * 64 + (lid >> 3);       // XCD-chunked, bijective
  const int by = swz >> 3, bx = swz & 7;
  const long m0 = (long)by * 128, n0 = (long)bx * 128;

  const int srow = tid >> 3, scu = tid & 7, sc = scu ^ (srow & 7);
  f32x4 acc[4][4] = {};

  for (int k0 = 0; k0 < K; k0 += 64) {
#pragma unroll
    for (int p = 0; p < 4; ++p) {
      int u = p * 256 + tid;
      int row = srow + p * 32;
      gload_lds16(A + (m0 + row) * K + k0 + sc * 8, (char*)As + u * 16);
      gload_lds16(Bm + (n0 + row) * K + k0 + sc * 8, (char*)Bs + u * 16);
    }
    __syncthreads();
    bf16x8 af[4][2], bfr[4][2];
#pragma unroll
    for (int i = 0; i < 4; ++i) {
#pragma unroll
      for (int kk = 0; kk < 2; ++kk) {
        int ua = ((kk * 4 + g) ^ (l15 & 7));
        af[i][kk]  = bc8(*(const s16x8*)&As[(wr * 64 + i * 16 + l15) * 64 + ua * 8]);
        bfr[i][kk] = bc8(*(const s16x8*)&Bs[(wc * 64 + i * 16 + l15) * 64 + ua * 8]);
      }
    }
#pragma unroll
    for (int mi = 0; mi < 4; ++mi)
#pragma unroll
      for (int ni = 0; ni < 4; ++ni) {
        acc[mi][ni] = mfma_bf(af[mi][0], bfr[ni][0], acc[mi][ni]);
        acc[mi][ni] = mfma_bf(af[mi][1], bfr[ni][1], acc[mi][ni]);
      }
    __syncthreads();
  }

#pragma unroll
  for (int mi = 0; mi < 4; ++mi)
#pragma unroll
    for (int ni = 0; ni < 4; ++ni) {
      long col = n0 + wc * 64 + ni * 16 + l15;
#pragma unroll
      for (int r = 0; r < 4; ++r) {
        long row = m0 + wr * 64 + mi * 16 + g * 4 + r;
        Cf[row * N + col] = acc[mi][ni][r] + bias[col];
      }
    }
}

// ---------- MFMA flash attention (fp16, KVBLK=256, 8 rounds, 512 thr) ----------
// r23/r24 kernel verbatim (banked, 95.7 us).
__global__ __launch_bounds__(512) void k_flash(
    const unsigned short* __restrict__ Qf, const unsigned short* __restrict__ Kf,
    const unsigned short* __restrict__ Vt, unsigned short* __restrict__ o) {
  __shared__ unsigned short KS[2][256 * 64];
  __shared__ unsigned short VtS[2][64 * 256];
  const int tid = threadIdx.x;
  const int lane = tid & 63, wid = tid >> 6;       // wid 0..7
  const int l15 = lane & 15, g = lane >> 4;
  const int j = blockIdx.x;                        // 512 blocks
  const int c = j & 7, s = j >> 3;                 // s 0..63
  const int bh = ((s >> 3) << 3) | c;              // bijective: bh in [0,64)
  const int qt = s & 7;
  const int b = bh >> 4, h = bh & 15;
  const int q0 = qt * 256 + wid * 32;
  const long slab = (long)bh * 131072;

  const long qrowA = slab + (long)(q0 + l15) * 64;
  const long qrowB = slab + (long)(q0 + 16 + l15) * 64;
  f16x8 qa0 = hc8(*(const s16x8*)&Qf[qrowA + g * 8]);
  f16x8 qa1 = hc8(*(const s16x8*)&Qf[qrowA + 32 + g * 8]);
  f16x8 qb0 = hc8(*(const s16x8*)&Qf[qrowB + g * 8]);
  f16x8 qb1 = hc8(*(const s16x8*)&Qf[qrowB + 32 + g * 8]);

  const u32x4 ones_raw = {0x3c003c00u, 0x3c003c00u, 0x3c003c00u, 0x3c003c00u};
  const f16x8 ones = __builtin_bit_cast(f16x8, ones_raw);

  f32x4 ova[4] = {}, ovb[4] = {};
  f32x4 lacA = {}, lacB = {};              // softmax denominators (via ones-MFMA)
  float mrunA = -1e30f, mrunB = -1e30f;

  const int cK = (tid & 7) ^ ((tid >> 3) & 7);
  const int cV = (tid & 31) ^ ((tid >> 5) & 7);
  const unsigned short* kSrc = Kf + slab + (long)(tid >> 3) * 64 + cK * 8;
  const unsigned short* vSrc = Vt + slab + (long)(tid >> 5) * 2048 + cV * 8;

  auto stage = [&](int buf) {
#pragma unroll
    for (int p = 0; p < 4; ++p) {
      gload_lds16(kSrc + p * 4096,  (char*)&KS[buf][0]  + (p * 512 + tid) * 16);
      gload_lds16(vSrc + p * 32768, (char*)&VtS[buf][0] + (p * 512 + tid) * 16);
    }
    kSrc += 16384;  // next 256-key group: 256 rows x 64
    vSrc += 256;    // next 256 keys along the 2048-key rows
  };

  stage(0);
  __syncthreads();                  // round 0 fully resident (all waves)

  for (int t = 0; t < 8; ++t) {
    const int cur = t & 1;
    if (t < 7) stage(cur ^ 1);      // prefetch; drains at end-of-round barrier

#pragma unroll
    for (int hf = 0; hf < 2; ++hf) {   // two 128-key halves per barrier round
      // QK^T over 128 keys
      f32x4 sa[8], sb[8];
      __builtin_amdgcn_s_setprio(1);
#pragma unroll
      for (int kt = 0; kt < 8; ++kt) {
        f32x4 xa = {}, xb = {};
#pragma unroll
        for (int kk = 0; kk < 2; ++kk) {
          int row = hf * 128 + kt * 16 + l15;
          int uu = row * 8 + ((kk * 4 + g) ^ (row & 7));
          f16x8 kf = hc8(*(const s16x8*)&KS[cur][uu * 8]);
          xa = mfma_h(kf, kk ? qa1 : qa0, xa);
          xb = mfma_h(kf, kk ? qb1 : qb0, xb);
        }
        sa[kt] = xa; sb[kt] = xb;
      }
      __builtin_amdgcn_s_setprio(0);

      // per-query half max via v_max3 chains
      float ta = fmaxf(sa[0][0], sa[0][1]);
      ta = max3f(ta, sa[0][2], sa[0][3]);
      float tb = fmaxf(sb[0][0], sb[0][1]);
      tb = max3f(tb, sb[0][2], sb[0][3]);
#pragma unroll
      for (int kt = 1; kt < 8; ++kt) {
        ta = max3f(ta, sa[kt][0], sa[kt][1]);
        ta = max3f(ta, sa[kt][2], sa[kt][3]);
        tb = max3f(tb, sb[kt][0], sb[kt][1]);
        tb = max3f(tb, sb[kt][2], sb[kt][3]);
      }
      ta = fmaxf(ta, __shfl_xor(ta, 16)); ta = fmaxf(ta, __shfl_xor(ta, 32));
      tb = fmaxf(tb, __shfl_xor(tb, 16)); tb = fmaxf(tb, __shfl_xor(tb, 32));

      // defer-max (THR=8 in log2 units; P bounded by 2^8, fp16-safe)
      if (!__all(ta <= mrunA + 8.f && tb <= mrunB + 8.f)) {
        float mA = fmaxf(mrunA, ta), mB = fmaxf(mrunB, tb);
        float cA = exp2i(mrunA - mA), cB = exp2i(mrunB - mB);
        lacA *= cA; lacB *= cB;
#pragma unroll
        for (int dt = 0; dt < 4; ++dt) { ova[dt] *= cA; ovb[dt] *= cB; }
        mrunA = mA; mrunB = mB;
      }

      unsigned pa[8][2], pbv[8][2];
#pragma unroll
      for (int kt = 0; kt < 8; ++kt) {
        float a0 = exp2i(sa[kt][0] - mrunA), a1 = exp2i(sa[kt][1] - mrunA);
        float a2 = exp2i(sa[kt][2] - mrunA), a3 = exp2i(sa[kt][3] - mrunA);
        float b0 = exp2i(sb[kt][0] - mrunB), b1 = exp2i(sb[kt][1] - mrunB);
        float b2 = exp2i(sb[kt][2] - mrunB), b3 = exp2i(sb[kt][3] - mrunB);
        pa[kt][0]  = cvtpkh(a0, a1); pa[kt][1]  = cvtpkh(a2, a3);
        pbv[kt][0] = cvtpkh(b0, b1); pbv[kt][1] = cvtpkh(b2, b3);
      }

      // PV over this half's two 64-key subtiles (st = hf*2 + ktile)
      __builtin_amdgcn_s_setprio(1);
#pragma unroll
      for (int ktile = 0; ktile < 2; ++ktile) {
        int kb = ktile * 4;
#pragma unroll
        for (int h2 = 0; h2 < 2; ++h2) {
          u32x4 brawA = {pa[kb + h2][0], pa[kb + h2][1],
                         pa[kb + h2 + 2][0], pa[kb + h2 + 2][1]};
          u32x4 brawB = {pbv[kb + h2][0], pbv[kb + h2][1],
                         pbv[kb + h2 + 2][0], pbv[kb + h2 + 2][1]};
          f16x8 pfA = __builtin_bit_cast(f16x8, brawA);
          f16x8 pfB = __builtin_bit_cast(f16x8, brawB);
          lacA = mfma_h(ones, pfA, lacA);
          lacB = mfma_h(ones, pfB, lacB);
#pragma unroll
          for (int dt = 0; dt < 4; ++dt) {
            int d = dt * 16 + l15;
            int vv = d * 32 + (hf * 2 + ktile) * 8 + ((h2 * 4 + g) ^ (d & 7));
            f16x8 vf = hc8(*(const s16x8*)&VtS[cur][vv * 8]);
            ova[dt] = mfma_h(vf, pfA, ova[dt]);
            ovb[dt] = mfma_h(vf, pfB, ovb[dt]);
          }
        }
      }
      __builtin_amdgcn_s_setprio(0);
    }
    __syncthreads();   // drains this wave's prefetch + barriers all waves
  }

  // lacA/lacB: every lane already holds the full-key denominator for its query
  float rA = 1.0f / lacA[0], rB = 1.0f / lacB[0];
  long orowA = ((long)(b * 2048 + q0 + l15)) * 1024 + h * 64;
  long orowB = ((long)(b * 2048 + q0 + 16 + l15)) * 1024 + h * 64;
#pragma unroll
  for (int dt = 0; dt < 4; ++dt) {
    ushort4 wa, wb;
    wa.x = f2bf(ova[dt][0] * rA); wa.y = f2bf(ova[dt][1] * rA);
    wa.z = f2bf(ova[dt][2] * rA); wa.w = f2bf(ova[dt][3] * rA);
    wb.x = f2bf(ovb[dt][0] * rB); wb.y = f2bf(ovb[dt][1] * rB);
    wb.z = f2bf(ovb[dt][2] * rB); wb.w = f2bf(ovb[dt][3] * rB);
    *(ushort4*)&o[orowA + dt * 16 + g * 4] = wa;
    *(ushort4*)&o[orowB + dt * 16 + g * 4] = wb;
  }
}

// ---------- launcher ----------
extern "C" void kernel_launch(void* const* d_in, const int* in_sizes, int n_in,
                              void* d_out, int out_size, void* d_ws, size_t ws_size,
                              hipStream_t stream) {
  const float* x      = (const float*)d_in[0];
  const float* sin_t  = (const float*)d_in[1];
  const float* cos_t  = (const float*)d_in[2];
  const float* w_qkv  = (const float*)d_in[3];
  const float* w_proj = (const float*)d_in[4];
  const float* b_proj = (const float*)d_in[5];
  float* out = (float*)d_out;

  char* ws = (char*)d_ws;
  unsigned short* xb     = (unsigned short*)(ws);                 // 16 MiB
  unsigned short* wqkvb  = (unsigned short*)(ws + (16l << 20));   // 6 MiB
  unsigned short* wprojb = (unsigned short*)(ws + (22l << 20));   // 2 MiB
  unsigned short* Qf     = (unsigned short*)(ws + (24l << 20));   // 16 MiB
  unsigned short* Kf     = (unsigned short*)(ws + (40l << 20));   // 16 MiB
  unsigned short* Vb     = (unsigned short*)(ws + (56l << 20));   // 16 MiB
  unsigned short* Vt     = (unsigned short*)(ws + (72l << 20));   // 16 MiB
  unsigned short* ob     = xb;   // alias: xb dead after QKV GEMM

  k_cvt_all<<<12288, 256, 0, stream>>>(x, w_qkv, w_proj, xb, wqkvb, wprojb);

  k_gemm_qkv<<<dim3(24, 32), 512, 0, stream>>>(xb, wqkvb, Qf, Kf, Vb,
                                               sin_t, cos_t);
  k_vtrans<<<dim3(8, 64), 256, 0, stream>>>(Vb, Vt);
  k_flash<<<dim3(512), 512, 0, stream>>>(Qf, Kf, Vt, ob);
  k_gemm_proj<<<dim3(8, 64), 256, 0, stream>>>(ob, wprojb, out, b_proj,
                                               8192, 1024, 1024);
}